// Round 3
// baseline (468.885 us; speedup 1.0000x reference)
//
#include <hip/hip_runtime.h>
#include <math.h>

// NsNet2-style fused net on MI355X (gfx950).
// All activations batch-major [B, F] fp16; every layer is
// C[B,M] = A[B,K] @ W[M,K]^T via mfma_f32_16x16x32_f16, fp32 accum.
// Feature dims padded to multiples of 64: 257->320, 400->448, 600->640.
// GRU: input-side gates as one stacked GEMM (M=1344, z|r|n) writing Gi in
// FRAGMENT layout; hidden-side gates fused in gemm_gru_h (3 accumulators +
// gate math in epilogue, h_old read from the last-staged LDS A-tile).
// XCD-aware bt-chunked block swizzle: each XCD owns a 16-bt chunk (A-chunk
// 1.8 MB -> L2-resident) and iterates all mt for it.

#define B_TOTAL 16384
#define H16_TOTAL 3452928L   // fp16 weight elements
#define PREP_TOTAL 3460352L  // + 7424 bias floats

typedef _Float16 h8 __attribute__((ext_vector_type(8)));
typedef _Float16 h4 __attribute__((ext_vector_type(4)));
typedef float f4 __attribute__((ext_vector_type(4)));

#define GLL(g, l) __builtin_amdgcn_global_load_lds(                         \
    (const __attribute__((address_space(1))) void*)(g),                     \
    (__attribute__((address_space(3))) void*)(l), 16, 0, 0)

// XCD-aware swizzle: grid = 128 * NMT blocks (NMT in {5,7,10,21}), all
// divisible by 8. xcd = bid&7 gets bt in [xcd*16, xcd*16+16) x all mt.
__device__ inline void swz_bt_mt(int bid, int& bt, int& mt) {
  const int xcd = bid & 7;
  const int i = bid >> 3;
  bt = xcd * 16 + (i & 15);
  mt = i >> 4;
}

// ---------------- weight/bias prep tables ----------------
// jobs 0-15: weights (fp16 dst, padded Mp x Kp, dstOff == job cum offset);
// jobs 16-31: biases (fp32 dst, padded to Mp). Gate order z, r, n.
__constant__ int kJsrc[32] = {3, 5,6,7, 8,9,10, 17,18,19, 20,21,22, 29, 31, 33,
                              4, 11,12,13, 14,15,16, 23,24,25, 26,27,28, 30, 32, 34};
__constant__ int kJM[32]   = {400, 400,400,400, 400,400,400, 400,400,400, 400,400,400, 600, 600, 257,
                              400, 400,400,400, 400,400,400, 400,400,400, 400,400,400, 600, 600, 257};
__constant__ int kJK[32]   = {257, 400,400,400, 400,400,400, 400,400,400, 400,400,400, 400, 600, 600,
                              1,1,1,1, 1,1,1, 1,1,1, 1,1,1, 1, 1, 1};
__constant__ int kJKp[32]  = {320, 448,448,448, 448,448,448, 448,448,448, 448,448,448, 448, 640, 640,
                              1,1,1,1, 1,1,1, 1,1,1, 1,1,1, 1, 1, 1};
__constant__ long kJcum[33] = {0,143360,344064,544768,745472,946176,1146880,1347584,1548288,1748992,
  1949696,2150400,2351104,2551808,2838528,3248128,3452928,3453376,3453824,3454272,3454720,3455168,
  3455616,3456064,3456512,3456960,3457408,3457856,3458304,3458752,3459392,3460032,3460352};

struct SrcPtrs { const float* p[35]; };

__global__ __launch_bounds__(256) void prep_weights(SrcPtrs sp, _Float16* __restrict__ w16,
                                                    float* __restrict__ b32) {
  long w = (long)blockIdx.x * 256 + threadIdx.x;
  if (w >= PREP_TOTAL) return;
  int j = 0;
  #pragma unroll 1
  while (j < 31 && kJcum[j + 1] <= w) j++;
  long local = w - kJcum[j];
  int Kp = kJKp[j];
  int m = (int)(local / Kp);
  int k = (int)(local - (long)m * Kp);
  float v = 0.f;
  if (m < kJM[j] && k < kJK[j]) v = sp.p[kJsrc[j]][(long)m * kJK[j] + k];
  if (j < 16) w16[w] = (_Float16)v;
  else        b32[w - H16_TOTAL] = v;
}

// ---------------- transposes ----------------
// src [F, 16384] f32 -> dst [16384, Fp] fp16, zero pad f>=F.
__global__ __launch_bounds__(256) void transpose_f32_to_h16(const float* __restrict__ src,
                                                            _Float16* __restrict__ dst,
                                                            int F, int Fp) {
  __shared__ float t[32][33];
  const int nFT = Fp >> 5;
  const int ft = blockIdx.x % nFT;
  const int bt = blockIdx.x / nFT;
  const int ci = threadIdx.x & 31, ri = threadIdx.x >> 5;
  #pragma unroll
  for (int p = 0; p < 4; ++p) {
    int f = ft * 32 + ri + p * 8;
    float v = (f < F) ? src[(long)f * B_TOTAL + bt * 32 + ci] : 0.f;
    t[ri + p * 8][ci] = v;
  }
  __syncthreads();
  #pragma unroll
  for (int p = 0; p < 4; ++p) {
    int b = bt * 32 + ri + p * 8;
    dst[(long)b * Fp + ft * 32 + ci] = (_Float16)t[ci][ri + p * 8];
  }
}

// src [16384, 320] f32 -> dst [257, 16384] f32
__global__ __launch_bounds__(256) void transpose_out(const float* __restrict__ src,
                                                     float* __restrict__ dst) {
  __shared__ float t[32][33];
  const int nFT = 10;
  const int ft = blockIdx.x % nFT;
  const int bt = blockIdx.x / nFT;
  const int ci = threadIdx.x & 31, ri = threadIdx.x >> 5;
  #pragma unroll
  for (int p = 0; p < 4; ++p)
    t[ri + p * 8][ci] = src[(long)(bt * 32 + ri + p * 8) * 320 + ft * 32 + ci];
  __syncthreads();
  #pragma unroll
  for (int p = 0; p < 4; ++p) {
    int f = ft * 32 + ri + p * 8;
    if (f < 257) dst[(long)f * B_TOTAL + bt * 32 + ci] = t[ci][ri + p * 8];
  }
}

// ---------------- GEMM: C[B,M] = A[B,K] @ W[M,K]^T (+bias, act) ----------------
// Tile 128(batch) x 64(feat), BK=64, 4 waves (each 64x32), mfma 16x16x32 f16.
// Linear LDS, staged via global_load_lds width=16 (dest = wave base + lane*16).
// ACT: 0 none, 1 relu, 2 sigmoid. OUTF32: fp32 C. FRAGOUT: per-thread fragment
// layout [bt][mtile][tid][32] fp16 (consumed by gemm_gru_h with identical tiling).
template <int ACT, int OUTF32, int FRAGOUT>
__global__ __launch_bounds__(256) void gemm_tn(const _Float16* __restrict__ A,
                                               const _Float16* __restrict__ W,
                                               const float* __restrict__ bias,
                                               void* __restrict__ C, int K, int M) {
  __shared__ __align__(16) _Float16 As[128 * 64];
  __shared__ __align__(16) _Float16 Ws[64 * 64];
  const int tid = threadIdx.x;
  const int l = tid & 63;
  const int w = tid >> 6;
  int bt, mt;
  swz_bt_mt(blockIdx.x, bt, mt);
  const int wr = w >> 1, wc = w & 1;

  const _Float16* ag = A + (long)(bt * 128 + w * 32 + (l >> 3)) * K + (l & 7) * 8;
  const _Float16* wg = W + (long)(mt * 64 + w * 16 + (l >> 3)) * K + (l & 7) * 8;
  char* asb = (char*)As + w * 4096;
  char* wsb = (char*)Ws + w * 2048;

  f4 acc[4][2];
  #pragma unroll
  for (int i = 0; i < 4; ++i)
    #pragma unroll
    for (int jj = 0; jj < 2; ++jj) acc[i][jj] = (f4){0.f, 0.f, 0.f, 0.f};

  const h8* AsV = (const h8*)As;
  const h8* WsV = (const h8*)Ws;
  const int lg = l >> 4;
  const int arow = wr * 64 + (l & 15);
  const int wrow = wc * 32 + (l & 15);

  const int KT = K >> 6;
  for (int kt = 0; kt < KT; ++kt) {
    const _Float16* agk = ag + kt * 64;
    const _Float16* wgk = wg + kt * 64;
    #pragma unroll
    for (int i = 0; i < 4; ++i) GLL(agk + (long)i * 8 * K, asb + i * 1024);
    #pragma unroll
    for (int i = 0; i < 2; ++i) GLL(wgk + (long)i * 8 * K, wsb + i * 1024);
    __syncthreads();

    h8 bfr[2][2];
    #pragma unroll
    for (int fn = 0; fn < 2; ++fn) {
      bfr[fn][0] = WsV[(wrow + fn * 16) * 8 + lg];
      bfr[fn][1] = WsV[(wrow + fn * 16) * 8 + 4 + lg];
    }
    #pragma unroll
    for (int fm = 0; fm < 4; ++fm) {
      h8 a0 = AsV[(arow + fm * 16) * 8 + lg];
      h8 a1 = AsV[(arow + fm * 16) * 8 + 4 + lg];
      #pragma unroll
      for (int fn = 0; fn < 2; ++fn) {
        acc[fm][fn] = __builtin_amdgcn_mfma_f32_16x16x32_f16(a0, bfr[fn][0], acc[fm][fn], 0, 0, 0);
        acc[fm][fn] = __builtin_amdgcn_mfma_f32_16x16x32_f16(a1, bfr[fn][1], acc[fm][fn], 0, 0, 0);
      }
    }
    __syncthreads();
  }

  // epilogue; C/D frag: col=l&15, row=(l>>4)*4+reg
  const int colBase = mt * 64 + wc * 32 + (l & 15);
  const int rowBase = bt * 128 + wr * 64 + (l >> 4) * 4;
  _Float16* fragp = 0;
  if (FRAGOUT) fragp = (_Float16*)C + ((long)(bt * (M >> 6) + mt) * 256 + tid) * 32;
  #pragma unroll
  for (int fn = 0; fn < 2; ++fn) {
    const float bb = bias[colBase + fn * 16];
    #pragma unroll
    for (int fm = 0; fm < 4; ++fm) {
      f4 xv;
      #pragma unroll
      for (int r = 0; r < 4; ++r) {
        float x = acc[fm][fn][r] + bb;
        if (ACT == 1) x = fmaxf(x, 0.f);
        if (ACT == 2) x = 1.f / (1.f + __expf(-x));
        xv[r] = x;
      }
      if (FRAGOUT) {
        h4 v; v[0] = (_Float16)xv[0]; v[1] = (_Float16)xv[1];
        v[2] = (_Float16)xv[2]; v[3] = (_Float16)xv[3];
        *(h4*)(fragp + (fm * 2 + fn) * 4) = v;
      } else {
        #pragma unroll
        for (int r = 0; r < 4; ++r) {
          const long off = (long)(rowBase + fm * 16 + r) * M + colBase + fn * 16;
          if (OUTF32) ((float*)C)[off] = xv[r];
          else        ((_Float16*)C)[off] = (_Float16)xv[r];
        }
      }
    }
  }
}

// ---------------- fused GRU hidden-side GEMM + gate combine ----------------
// A = h_old [B,448]; W = Wh stacked [1344,448] (z|r|n); bh = [1344] (bhz|bhr|bhn);
// Gi = fragment-layout [bt][21][tid][32] fp16 (bi already added);
// Hn = h_new [B,448] fp16.  Grid 128 x 7, K=448.
__global__ __launch_bounds__(256) void gemm_gru_h(const _Float16* __restrict__ A,
                                                  const _Float16* __restrict__ W,
                                                  const float* __restrict__ bh,
                                                  const _Float16* __restrict__ Gi,
                                                  _Float16* __restrict__ Hn) {
  constexpr int K = 448;
  __shared__ __align__(16) _Float16 As[128 * 64];
  __shared__ __align__(16) _Float16 Ws[3][64 * 64];
  const int tid = threadIdx.x;
  const int l = tid & 63;
  const int w = tid >> 6;
  int bt, mt;
  swz_bt_mt(blockIdx.x, bt, mt);    // mt in [0,7): 64-col slice of h
  const int wr = w >> 1, wc = w & 1;

  const _Float16* ag = A + (long)(bt * 128 + w * 32 + (l >> 3)) * K + (l & 7) * 8;
  const _Float16* wg = W + (long)(mt * 64 + w * 16 + (l >> 3)) * K + (l & 7) * 8;
  char* asb = (char*)As + w * 4096;

  f4 acc[3][4][2];
  #pragma unroll
  for (int g = 0; g < 3; ++g)
    #pragma unroll
    for (int i = 0; i < 4; ++i)
      #pragma unroll
      for (int jj = 0; jj < 2; ++jj) acc[g][i][jj] = (f4){0.f, 0.f, 0.f, 0.f};

  const h8* AsV = (const h8*)As;
  const h8* WsV = (const h8*)Ws;
  const int lg = l >> 4;
  const int arow = wr * 64 + (l & 15);
  const int wrow = wc * 32 + (l & 15);

  // rotate K-tiles so the LAST staged A-tile is kt==mt (h_old cols for epilogue)
  for (int kti = 0; kti < 7; ++kti) {
    const int kt = (mt + 1 + kti) % 7;
    const _Float16* agk = ag + kt * 64;
    const _Float16* wgk = wg + kt * 64;
    #pragma unroll
    for (int i = 0; i < 4; ++i) GLL(agk + (long)i * 8 * K, asb + i * 1024);
    #pragma unroll
    for (int g = 0; g < 3; ++g) {
      char* wsb = (char*)Ws + g * 8192 + w * 2048;
      GLL(wgk + (long)g * 200704, wsb);
      GLL(wgk + (long)g * 200704 + 8 * K, wsb + 1024);
    }
    __syncthreads();

    h8 bfr[3][2][2];
    #pragma unroll
    for (int g = 0; g < 3; ++g)
      #pragma unroll
      for (int fn = 0; fn < 2; ++fn) {
        bfr[g][fn][0] = WsV[g * 512 + (wrow + fn * 16) * 8 + lg];
        bfr[g][fn][1] = WsV[g * 512 + (wrow + fn * 16) * 8 + 4 + lg];
      }
    #pragma unroll
    for (int fm = 0; fm < 4; ++fm) {
      h8 a0 = AsV[(arow + fm * 16) * 8 + lg];
      h8 a1 = AsV[(arow + fm * 16) * 8 + 4 + lg];
      #pragma unroll
      for (int g = 0; g < 3; ++g)
        #pragma unroll
        for (int fn = 0; fn < 2; ++fn) {
          acc[g][fm][fn] = __builtin_amdgcn_mfma_f32_16x16x32_f16(a0, bfr[g][fn][0], acc[g][fm][fn], 0, 0, 0);
          acc[g][fm][fn] = __builtin_amdgcn_mfma_f32_16x16x32_f16(a1, bfr[g][fn][1], acc[g][fm][fn], 0, 0, 0);
        }
    }
    __syncthreads();
  }

  // Gi fragments: same tiling/wave decomposition as producer -> dense loads
  h8 gi8[3][4];
  const long gbase = ((long)(bt * 21) * 256 + tid) * 32;
  #pragma unroll
  for (int g = 0; g < 3; ++g) {
    const h8* gp = (const h8*)(Gi + gbase + (long)(g * 7 + mt) * 8192);
    #pragma unroll
    for (int q = 0; q < 4; ++q) gi8[g][q] = gp[q];
  }

  const int jloc = wc * 32 + (l & 15);
  const int rowLoc = wr * 64 + (l >> 4) * 4;
  const long rowGlob = (long)bt * 128 + rowLoc;
  #pragma unroll
  for (int fn = 0; fn < 2; ++fn) {
    const int j = mt * 64 + jloc + fn * 16;
    const float bz = bh[j], br = bh[448 + j], bn = bh[896 + j];
    #pragma unroll
    for (int fm = 0; fm < 4; ++fm) {
      const int q = fm * 2 + fn;
      #pragma unroll
      for (int r = 0; r < 4; ++r) {
        const float giz = (float)gi8[0][q >> 1][(q & 1) * 4 + r];
        const float gir = (float)gi8[1][q >> 1][(q & 1) * 4 + r];
        const float gin = (float)gi8[2][q >> 1][(q & 1) * 4 + r];
        const float hz = acc[0][fm][fn][r] + bz + giz;
        const float hr = acc[1][fm][fn][r] + br + gir;
        const float hn = acc[2][fm][fn][r] + bn;
        const float rr = 1.f / (1.f + __expf(-hr));
        const float zz = 1.f / (1.f + __expf(-hz));
        const float nn = gin + rr * hn;
        const float th = 1.f - 2.f / (__expf(2.f * nn) + 1.f);  // tanh
        const float ho = (float)As[(rowLoc + fm * 16 + r) * 64 + jloc + fn * 16];
        Hn[(rowGlob + fm * 16 + r) * 448 + j] = (_Float16)((1.f - zz) * th + zz * ho);
      }
    }
  }
}

// ---------------- launch ----------------
extern "C" void kernel_launch(void* const* d_in, const int* in_sizes, int n_in,
                              void* d_out, int out_size, void* d_ws, size_t ws_size,
                              hipStream_t stream) {
  char* ws = (char*)d_ws;
  _Float16* W16  = (_Float16*)(ws);                 // 3,452,928 fp16
  float*    BIAS = (float*)(ws + 6905856L);         // 7,424 f32
  _Float16* buf0 = (_Float16*)(ws + 6935552L);      // Gi frag [B,1344]; later f32 outT
  _Float16* buf2 = (_Float16*)(ws + 50975744L);     // xT [B,320] -> y1 [B,640]
  _Float16* buf3 = (_Float16*)(ws + 71947264L);     // fc1 [B,448] -> y2 [B,640]
  _Float16* buf4 = (_Float16*)(ws + 92918784L);     // h1_old -> h2_new [B,448]
  _Float16* buf5 = (_Float16*)(ws + 107598848L);    // h2_old [B,448]
  _Float16* buf6 = (_Float16*)(ws + 122278912L);    // h1_new [B,448]
  float* outT = (float*)buf0;                       // [B,320] f32
  if (ws_size < 136958976UL) return;  // loud failure rather than OOB

  SrcPtrs sp;
  for (int i = 0; i < 35; ++i) sp.p[i] = (const float*)d_in[i];

  prep_weights<<<dim3(13517), dim3(256), 0, stream>>>(sp, W16, BIAS);
  transpose_f32_to_h16<<<dim3(10 * 512), dim3(256), 0, stream>>>((const float*)d_in[0], buf2, 257, 320);
  transpose_f32_to_h16<<<dim3(14 * 512), dim3(256), 0, stream>>>((const float*)d_in[1], buf4, 400, 448);
  transpose_f32_to_h16<<<dim3(14 * 512), dim3(256), 0, stream>>>((const float*)d_in[2], buf5, 400, 448);

  // fc1: [B,320] @ [448,320]^T -> [B,448]
  gemm_tn<0, 0, 0><<<dim3(128 * 7), dim3(256), 0, stream>>>(buf2, W16, BIAS, (void*)buf3, 320, 448);
  // GRU1: Gi (frag layout), then fused h-side + gate combine
  gemm_tn<0, 0, 1><<<dim3(128 * 21), dim3(256), 0, stream>>>(buf3, W16 + 143360, BIAS + 448, (void*)buf0, 448, 1344);
  gemm_gru_h<<<dim3(128 * 7), dim3(256), 0, stream>>>(buf4, W16 + 745472, BIAS + 1792, buf0, buf6);
  // GRU2
  gemm_tn<0, 0, 1><<<dim3(128 * 21), dim3(256), 0, stream>>>(buf6, W16 + 1347584, BIAS + 3136, (void*)buf0, 448, 1344);
  gemm_gru_h<<<dim3(128 * 7), dim3(256), 0, stream>>>(buf5, W16 + 1949696, BIAS + 4480, buf0, buf4);
  // fc2 (relu), fc3 (relu), fc4 (sigmoid, fp32 out)
  gemm_tn<1, 0, 0><<<dim3(128 * 10), dim3(256), 0, stream>>>(buf4, W16 + 2551808, BIAS + 5824, (void*)buf2, 448, 640);
  gemm_tn<1, 0, 0><<<dim3(128 * 10), dim3(256), 0, stream>>>(buf2, W16 + 2838528, BIAS + 6464, (void*)buf3, 640, 640);
  gemm_tn<2, 1, 0><<<dim3(128 * 5), dim3(256), 0, stream>>>(buf3, W16 + 3248128, BIAS + 7104, (void*)outT, 640, 320);

  transpose_out<<<dim3(10 * 512), dim3(256), 0, stream>>>(outT, (float*)d_out);
}